// Round 13
// baseline (7905.215 us; speedup 1.0000x reference)
//
#include <hip/hip_runtime.h>
#include <math.h>

// Problem dims (fixed by setup_inputs)
#define B_ROWS 65536
#define DDIM   512
#define NG     4
#define NK     1024
#define NH     128
#define NA     7

// Tiling: 512 threads = 8 waves = 4 row-groups (TR=8) x 2 cw-groups.
// K-block 1 (k<384): full TC=8 (accA=64 VGPR). K-block 2 (k>=384): two
// TC=4 halves with a 32-reg accB each, folded into the argmax right away.
// Peak live ~120 <= the 128-reg class the allocator targets (2 blocks/CU).
// LDS trimmed to 65KB so two blocks co-reside -> 4 waves/SIMD.
#define BM       32
#define NTHREADS 512
#define TR       8
#define TC       8
#define KSPLIT   384            // OpenBLAS sgemm GEMM_Q K-block boundary

// LDS: resid [32][512] fp32 (64KB; also reused for h1/h2 in the MLP) +
// tiny aux (redS/redI/idx = 1KB).
#define OFF_AUX   (BM * DDIM * 4)            // 65536
#define LDS_BYTES (OFF_AUX + 1024)           // 66560 -> 2 blocks/CU

// ---------------------------------------------------------------------------
// 0.5 * ||c||^2 emulating numpy fp32 np.sum(C*C, axis=-1):
// pairwise_sum, AVX512 SIMD variant (vstep=16, PW_BLOCKSIZE=128).
// fp contract OFF: each square rounds before add.
// ---------------------------------------------------------------------------
__global__ void rvq_norms_np(const float* __restrict__ cb,
                             float* __restrict__ halfnorm) {
#pragma clang fp contract(off)
    int k = blockIdx.x * blockDim.x + threadIdx.x;
    if (k >= NG * NK) return;
    const float* c = cb + (size_t)k * DDIM;
    float blk[4];
#pragma unroll
    for (int b = 0; b < 4; ++b) {
        const float* p = c + b * 128;
        float s[16];
#pragma unroll
        for (int l = 0; l < 16; ++l) {
            float x0 = p[l],      x1 = p[l + 16], x2 = p[l + 32], x3 = p[l + 48];
            float x4 = p[l + 64], x5 = p[l + 80], x6 = p[l + 96], x7 = p[l + 112];
            float pa = x0 * x0 + x4 * x4;
            float pb = x1 * x1 + x5 * x5;
            float pc = x2 * x2 + x6 * x6;
            float pd = x3 * x3 + x7 * x7;
            s[l] = (pa + pb) + (pc + pd);
        }
        float h[8];
#pragma unroll
        for (int l = 0; l < 8; ++l) h[l] = s[l] + s[l + 8];
        float q[4];
#pragma unroll
        for (int l = 0; l < 4; ++l) q[l] = h[l] + h[l + 4];
        float r0 = q[0] + q[2];
        float r1 = q[1] + q[3];
        blk[b] = r0 + r1;
    }
    float total = (blk[0] + blk[1]) + (blk[2] + blk[3]);
    halfnorm[k] = 0.5f * total;
}

// ---------------------------------------------------------------------------
// Codebook transpose: cbT[g][d][cw] = cb[g][cw][d]. Coalesced both sides via
// a padded 32x32 LDS tile. Bit-exact copy.
// ---------------------------------------------------------------------------
__global__ void rvq_transpose(const float* __restrict__ cb,
                              float* __restrict__ cbT) {
    __shared__ float tile[32][33];
    const int g   = blockIdx.z;
    const int cw0 = blockIdx.x * 32;
    const int d0  = blockIdx.y * 32;
    const int tx  = threadIdx.x, ty = threadIdx.y;   // 32 x 8
    const float* src = cb + ((size_t)g * NK + cw0) * DDIM + d0;
#pragma unroll
    for (int ph = 0; ph < 4; ++ph)
        tile[ty + ph * 8][tx] = src[(size_t)(ty + ph * 8) * DDIM + tx];
    __syncthreads();
    float* dst = cbT + ((size_t)g * DDIM + d0) * NK + cw0;
#pragma unroll
    for (int ph = 0; ph < 4; ++ph)
        dst[(size_t)(ty + ph * 8) * NK + tx] = tile[tx][ty + ph * 8];
}

// 4-k step, full TC=8 (K-block 1). A: TR wave-uniform LDS b128 broadcasts.
// BV: [0..3] = cw0+{0..3}, [4..7] = cw0+256+{0..3}. dd asc within step,
// steps asc -> strictly ascending k per accumulator chain.
#define STEP8(ACC, BV, KB)                                                   \
    _Pragma("unroll")                                                        \
    for (int r = 0; r < TR; ++r) {                                           \
        float4 av = *(const float4*)&resid[(r0 + r) * DDIM + (KB)];          \
        const float* avf = (const float*)&av;                                \
        _Pragma("unroll")                                                    \
        for (int dd = 0; dd < 4; ++dd) {                                     \
            const float a = avf[dd];                                         \
            const float* g1 = (const float*)&BV[dd];                         \
            const float* g2 = (const float*)&BV[4 + dd];                     \
            ACC[r][0] = fmaf(a, g1[0], ACC[r][0]);                           \
            ACC[r][1] = fmaf(a, g1[1], ACC[r][1]);                           \
            ACC[r][2] = fmaf(a, g1[2], ACC[r][2]);                           \
            ACC[r][3] = fmaf(a, g1[3], ACC[r][3]);                           \
            ACC[r][4] = fmaf(a, g2[0], ACC[r][4]);                           \
            ACC[r][5] = fmaf(a, g2[1], ACC[r][5]);                           \
            ACC[r][6] = fmaf(a, g2[2], ACC[r][6]);                           \
            ACC[r][7] = fmaf(a, g2[3], ACC[r][7]);                           \
        }                                                                    \
    }

#define LOADB8(DST, ROW)                                                     \
    _Pragma("unroll")                                                        \
    for (int dd = 0; dd < 4; ++dd) {                                         \
        DST[dd]     = *(const float4*)(bp + (size_t)((ROW) + dd) * NK);      \
        DST[4 + dd] = *(const float4*)(bp + (size_t)((ROW) + dd) * NK + 256);\
    }

// 4-k step, one TC=4 half (K-block 2). BH[dd] = row (KB+dd), 4 consecutive
// cols at offset JOFF (0 or 256) from cw0.
#define STEP4(ACC, BH, KB)                                                   \
    _Pragma("unroll")                                                        \
    for (int r = 0; r < TR; ++r) {                                           \
        float4 av = *(const float4*)&resid[(r0 + r) * DDIM + (KB)];          \
        const float* avf = (const float*)&av;                                \
        _Pragma("unroll")                                                    \
        for (int dd = 0; dd < 4; ++dd) {                                     \
            const float a = avf[dd];                                         \
            const float* bf = (const float*)&BH[dd];                         \
            ACC[r][0] = fmaf(a, bf[0], ACC[r][0]);                           \
            ACC[r][1] = fmaf(a, bf[1], ACC[r][1]);                           \
            ACC[r][2] = fmaf(a, bf[2], ACC[r][2]);                           \
            ACC[r][3] = fmaf(a, bf[3], ACC[r][3]);                           \
        }                                                                    \
    }

#define LOADB4(DST, ROW, JOFF)                                               \
    _Pragma("unroll")                                                        \
    for (int dd = 0; dd < 4; ++dd)                                           \
        DST[dd] = *(const float4*)(bp + (size_t)((ROW) + dd) * NK + (JOFF));

// ---------------------------------------------------------------------------
// Fused: residual VQ (4 stages, np-fp32-emulated scoring; B from transposed
// codebook in global/L2, A from LDS, barrier-free k-loop) + reference-order
// quantized sum + straight-through + MLP (512->128->128->7).
// ---------------------------------------------------------------------------
__global__ __launch_bounds__(NTHREADS, 4) void rvq_mlp_fused(
    const float* __restrict__ z, const float* __restrict__ cb,
    const float* __restrict__ cbT, const float* __restrict__ halfnorm,
    const float* __restrict__ w1, const float* __restrict__ b1,
    const float* __restrict__ w2, const float* __restrict__ b2,
    const float* __restrict__ w3, const float* __restrict__ b3,
    float* __restrict__ out) {
    extern __shared__ char smem[];
    float* resid = (float*)smem;                       // [BM][DDIM]; later h1/h2
    float* redS  = (float*)(smem + OFF_AUX);           // [2][BM]
    int*   redI  = (int*)(smem + OFF_AUX + 256);       // [2][BM]
    int*   idx_s = (int*)(smem + OFF_AUX + 512);       // [NG][BM]

    const int tid = threadIdx.x;
    const size_t row0 = (size_t)blockIdx.x * BM;

    // ---- 1) load z tile into LDS ----
    {
        const float4* src = (const float4*)(z + row0 * DDIM);
        float4* dst = (float4*)resid;
#pragma unroll
        for (int i = 0; i < (BM * DDIM / 4) / NTHREADS; ++i)
            dst[tid + i * NTHREADS] = src[tid + i * NTHREADS];
    }
    __syncthreads();

    const int cg    = tid & 63;       // lane
    const int wv    = tid >> 6;       // wave 0..7
    const int rgrp  = wv & 3;         // row-group (8 rows each)
    const int cwgrp = wv >> 2;        // cw-group (512 cw each)
    const int r0    = rgrp * TR;
    const int cw0   = cwgrp * 512 + cg * 4;   // lane cols: cw0+{0..3}, +256+{0..3}

    // ---- 2) residual VQ stages ----
    for (int g = 0; g < NG; ++g) {
        const float* Cg = cb + (size_t)g * NK * DDIM;      // row-major (updates)
        const float* Tg = cbT + (size_t)g * DDIM * NK;     // transposed (scores)
        const float* hn = halfnorm + g * NK;
        const float* bp = Tg + cw0;

        // ---- K-block 1: k = 0..383, all 8 codewords (accA = 64 regs) ----
        float accA[TR][TC];
#pragma unroll
        for (int r = 0; r < TR; ++r)
#pragma unroll
            for (int j = 0; j < TC; ++j) accA[r][j] = 0.f;
        {
            float4 bv[8];
#pragma unroll 2
            for (int d4 = 0; d4 < KSPLIT; d4 += 4) {
                LOADB8(bv, d4)
                STEP8(accA, bv, d4)
            }
        }

        float sb[TR]; int ib[TR];
#pragma unroll
        for (int r = 0; r < TR; ++r) { sb[r] = -3.4e38f; ib[r] = 0; }

        // ---- K-block 2, half 1: j=0..3 (cols cw0+{0..3}); fold right away
        //      (frees accB and accA[:,0..3]; candidates ascending) ----
        {
            float accB[TR][4];
#pragma unroll
            for (int r = 0; r < TR; ++r)
#pragma unroll
                for (int j = 0; j < 4; ++j) accB[r][j] = 0.f;
            float4 bh[4];
#pragma unroll 2
            for (int d4 = KSPLIT; d4 < DDIM; d4 += 4) {
                LOADB4(bh, d4, 0)
                STEP4(accB, bh, d4)
            }
#pragma unroll
            for (int j = 0; j < 4; ++j) {
                const int cod = cw0 + j;
                const float hnv = hn[cod];
#pragma unroll
                for (int r = 0; r < TR; ++r) {
                    float s = (accA[r][j] + accB[r][j]) - hnv;
                    if (s > sb[r]) { sb[r] = s; ib[r] = cod; }
                }
            }
        }

        // ---- K-block 2, half 2: j=4..7 (cols cw0+256+{0..3}) ----
        {
            float accB[TR][4];
#pragma unroll
            for (int r = 0; r < TR; ++r)
#pragma unroll
                for (int j = 0; j < 4; ++j) accB[r][j] = 0.f;
            float4 bh[4];
#pragma unroll 2
            for (int d4 = KSPLIT; d4 < DDIM; d4 += 4) {
                LOADB4(bh, d4, 256)
                STEP4(accB, bh, d4)
            }
#pragma unroll
            for (int j = 0; j < 4; ++j) {
                const int cod = cw0 + 256 + j;
                const float hnv = hn[cod];
#pragma unroll
                for (int r = 0; r < TR; ++r) {
                    float s = (accA[r][4 + j] + accB[r][j]) - hnv;
                    if (s > sb[r]) { sb[r] = s; ib[r] = cod; }
                }
            }
        }

        // ---- butterfly argmax within wave (ties -> lower index) ----
#pragma unroll
        for (int m = 32; m >= 1; m >>= 1) {
#pragma unroll
            for (int r = 0; r < TR; ++r) {
                float os = __shfl_xor(sb[r], m, 64);
                int   oi = __shfl_xor(ib[r], m, 64);
                if (os > sb[r] || (os == sb[r] && oi < ib[r])) {
                    sb[r] = os; ib[r] = oi;
                }
            }
        }
        if (cg == 0) {
#pragma unroll
            for (int r = 0; r < TR; ++r) {
                redS[cwgrp * BM + r0 + r] = sb[r];
                redI[cwgrp * BM + r0 + r] = ib[r];
            }
        }
        __syncthreads();
        // combine the two cw-groups per row (global first-occurrence ties)
        if (tid < BM) {
            float sA = redS[tid], sB = redS[BM + tid];
            int   iA = redI[tid], iB = redI[BM + tid];
            idx_s[g * BM + tid] =
                (sB > sA || (sB == sA && iB < iA)) ? iB : iA;
        }
        __syncthreads();

        // ---- residual -= chosen codeword (exact fp32); skip after last ----
        if (g < NG - 1) {
            const int row = tid >> 4;
            const int sub = tid & 15;
            const float4* crow =
                (const float4*)(Cg + (size_t)idx_s[g * BM + row] * DDIM);
            float4* rrow = (float4*)&resid[row * DDIM];
#pragma unroll
            for (int k = 0; k < 8; ++k) {
                int p = sub + k * 16;
                float4 rv = rrow[p], cv = crow[p];
                rv.x -= cv.x; rv.y -= cv.y; rv.z -= cv.z; rv.w -= cv.w;
                rrow[p] = rv;
            }
            __syncthreads();
        }
    }

    // ---- 3) st = z + (zq - z), zq in reference order (((0+q0)+q1)+q2)+q3 ----
    {
        const int row = tid >> 4;
        const int sub = tid & 15;
        const float4* zrow = (const float4*)(z + (row0 + row) * DDIM);
        float4* rrow = (float4*)&resid[row * DDIM];
        const float4* c0 = (const float4*)(cb + ((size_t)0 * NK + idx_s[0 * BM + row]) * DDIM);
        const float4* c1 = (const float4*)(cb + ((size_t)1 * NK + idx_s[1 * BM + row]) * DDIM);
        const float4* c2 = (const float4*)(cb + ((size_t)2 * NK + idx_s[2 * BM + row]) * DDIM);
        const float4* c3 = (const float4*)(cb + ((size_t)3 * NK + idx_s[3 * BM + row]) * DDIM);
#pragma unroll
        for (int k = 0; k < 8; ++k) {
            int p = sub + k * 16;
            float4 q0 = c0[p], q1 = c1[p], q2 = c2[p], q3 = c3[p];
            float4 q;
            q.x = ((q0.x + q1.x) + q2.x) + q3.x;
            q.y = ((q0.y + q1.y) + q2.y) + q3.y;
            q.z = ((q0.z + q1.z) + q2.z) + q3.z;
            q.w = ((q0.w + q1.w) + q2.w) + q3.w;
            float4 zv = zrow[p];
            float4 st;
            st.x = zv.x + (q.x - zv.x);
            st.y = zv.y + (q.y - zv.y);
            st.z = zv.z + (q.z - zv.z);
            st.w = zv.w + (q.w - zv.w);
            rrow[p] = st;
        }
    }
    __syncthreads();

    const int colg = tid & 31;
    const int rowg = tid >> 5;
    const int c0_  = colg * 4;
    const int hr0  = rowg * 2;

    float* h1buf = resid;              // [BM][NH], overwrites st rows 0..7
    float* h2buf = resid + BM * NH;    // [BM][NH], overwrites st rows 8..15

    // ---- 4) h1 = relu(st @ w1 + b1) -> regs -> barrier -> h1buf ----
    {
        float acc[2][4] = {{0.f, 0.f, 0.f, 0.f}, {0.f, 0.f, 0.f, 0.f}};
        for (int d = 0; d < DDIM; d += 4) {
            float4 a0 = *(const float4*)&resid[hr0 * DDIM + d];
            float4 a1 = *(const float4*)&resid[(hr0 + 1) * DDIM + d];
            float a0f[4] = {a0.x, a0.y, a0.z, a0.w};
            float a1f[4] = {a1.x, a1.y, a1.z, a1.w};
#pragma unroll
            for (int dd = 0; dd < 4; ++dd) {
                float4 wv2 = *(const float4*)&w1[(size_t)(d + dd) * NH + c0_];
                acc[0][0] = fmaf(a0f[dd], wv2.x, acc[0][0]);
                acc[0][1] = fmaf(a0f[dd], wv2.y, acc[0][1]);
                acc[0][2] = fmaf(a0f[dd], wv2.z, acc[0][2]);
                acc[0][3] = fmaf(a0f[dd], wv2.w, acc[0][3]);
                acc[1][0] = fmaf(a1f[dd], wv2.x, acc[1][0]);
                acc[1][1] = fmaf(a1f[dd], wv2.y, acc[1][1]);
                acc[1][2] = fmaf(a1f[dd], wv2.z, acc[1][2]);
                acc[1][3] = fmaf(a1f[dd], wv2.w, acc[1][3]);
            }
        }
        float4 bv = *(const float4*)&b1[c0_];
        float bf[4] = {bv.x, bv.y, bv.z, bv.w};
        __syncthreads();   // all st reads complete before overwriting resid
#pragma unroll
        for (int r = 0; r < 2; ++r) {
            float4 o;
            o.x = fmaxf(acc[r][0] + bf[0], 0.f);
            o.y = fmaxf(acc[r][1] + bf[1], 0.f);
            o.z = fmaxf(acc[r][2] + bf[2], 0.f);
            o.w = fmaxf(acc[r][3] + bf[3], 0.f);
            *(float4*)&h1buf[(hr0 + r) * NH + c0_] = o;
        }
    }
    __syncthreads();

    // ---- 5) h2 = relu(h1 @ w2 + b2) -> regs -> barrier -> h2buf ----
    {
        float acc[2][4] = {{0.f, 0.f, 0.f, 0.f}, {0.f, 0.f, 0.f, 0.f}};
        for (int d = 0; d < NH; d += 4) {
            float4 a0 = *(const float4*)&h1buf[hr0 * NH + d];
            float4 a1 = *(const float4*)&h1buf[(hr0 + 1) * NH + d];
            float a0f[4] = {a0.x, a0.y, a0.z, a0.w};
            float a1f[4] = {a1.x, a1.y, a1.z, a1.w};
#pragma unroll
            for (int dd = 0; dd < 4; ++dd) {
                float4 wv2 = *(const float4*)&w2[(size_t)(d + dd) * NH + c0_];
                acc[0][0] = fmaf(a0f[dd], wv2.x, acc[0][0]);
                acc[0][1] = fmaf(a0f[dd], wv2.y, acc[0][1]);
                acc[0][2] = fmaf(a0f[dd], wv2.z, acc[0][2]);
                acc[0][3] = fmaf(a0f[dd], wv2.w, acc[0][3]);
                acc[1][0] = fmaf(a1f[dd], wv2.x, acc[1][0]);
                acc[1][1] = fmaf(a1f[dd], wv2.y, acc[1][1]);
                acc[1][2] = fmaf(a1f[dd], wv2.z, acc[1][2]);
                acc[1][3] = fmaf(a1f[dd], wv2.w, acc[1][3]);
            }
        }
        float4 bv = *(const float4*)&b2[c0_];
        float bf[4] = {bv.x, bv.y, bv.z, bv.w};
        __syncthreads();   // all h1 reads complete (h2buf overlaps nothing of h1)
#pragma unroll
        for (int r = 0; r < 2; ++r) {
            float4 o;
            o.x = fmaxf(acc[r][0] + bf[0], 0.f);
            o.y = fmaxf(acc[r][1] + bf[1], 0.f);
            o.z = fmaxf(acc[r][2] + bf[2], 0.f);
            o.w = fmaxf(acc[r][3] + bf[3], 0.f);
            *(float4*)&h2buf[(hr0 + r) * NH + c0_] = o;
        }
    }
    __syncthreads();

    // ---- 6) out = h2 @ w3 + b3 ----
    if (tid < BM * NA) {
        const int r = tid / NA;
        const int a = tid - r * NA;
        const float* h2r = &h2buf[r * NH];
        float s = b3[a];
        for (int h = 0; h < NH; ++h)
            s = fmaf(h2r[h], w3[(size_t)h * NA + a], s);
        out[(row0 + r) * NA + a] = s;
    }
}

extern "C" void kernel_launch(void* const* d_in, const int* in_sizes, int n_in,
                              void* d_out, int out_size, void* d_ws, size_t ws_size,
                              hipStream_t stream) {
    const float* z  = (const float*)d_in[0];
    const float* cb = (const float*)d_in[1];
    const float* w1 = (const float*)d_in[2];
    const float* b1 = (const float*)d_in[3];
    const float* w2 = (const float*)d_in[4];
    const float* b2 = (const float*)d_in[5];
    const float* w3 = (const float*)d_in[6];
    const float* b3 = (const float*)d_in[7];
    float* out = (float*)d_out;

    float* halfnorm = (float*)d_ws;             // NG*NK floats = 16 KB
    float* cbT      = (float*)d_ws + NG * NK;   // NG*DDIM*NK floats = 8 MB

    (void)hipFuncSetAttribute((const void*)rvq_mlp_fused,
                              hipFuncAttributeMaxDynamicSharedMemorySize,
                              LDS_BYTES);

    rvq_norms_np<<<dim3((NG * NK + 255) / 256), dim3(256), 0, stream>>>(cb, halfnorm);
    rvq_transpose<<<dim3(NK / 32, DDIM / 32, NG), dim3(32, 8), 0, stream>>>(cb, cbT);
    rvq_mlp_fused<<<dim3(B_ROWS / BM), dim3(NTHREADS), LDS_BYTES, stream>>>(
        z, cb, cbT, halfnorm, w1, b1, w2, b2, w3, b3, out);
}

// Round 14
// 4120.592 us; speedup vs baseline: 1.9185x; 1.9185x over previous
//
#include <hip/hip_runtime.h>
#include <math.h>

// Problem dims (fixed by setup_inputs)
#define B_ROWS 65536
#define DDIM   512
#define NG     4
#define NK     1024
#define NH     128
#define NA     7

// Tiling: 512 threads = 8 waves = 4 row-groups (TR=8) x 2 cw-groups.
// K-block 1 (k<384): full TC=8 (accA=64 VGPR). K-block 2 (k>=384): two
// TC=4 halves with a 32-reg accB each, folded into the argmax right away.
// Peak live ~116 < 128. __launch_bounds__(512,2) -> 128-reg class (measured:
// (512,1)/(512,2)->128, (512,4)->64, 1024-thread->64). LDS 66.5KB -> two
// blocks/CU co-resident -> 4 waves/SIMD.
#define BM       32
#define NTHREADS 512
#define TR       8
#define TC       8
#define KSPLIT   384            // OpenBLAS sgemm GEMM_Q K-block boundary

// LDS: resid [32][512] fp32 (64KB; reused for h1/h2 in the MLP) +
// tiny aux (redS/redI/idx = 1KB).
#define OFF_AUX   (BM * DDIM * 4)            // 65536
#define LDS_BYTES (OFF_AUX + 1024)           // 66560 -> 2 blocks/CU

// ---------------------------------------------------------------------------
// 0.5 * ||c||^2 emulating numpy fp32 np.sum(C*C, axis=-1):
// pairwise_sum, AVX512 SIMD variant (vstep=16, PW_BLOCKSIZE=128).
// fp contract OFF: each square rounds before add.
// ---------------------------------------------------------------------------
__global__ void rvq_norms_np(const float* __restrict__ cb,
                             float* __restrict__ halfnorm) {
#pragma clang fp contract(off)
    int k = blockIdx.x * blockDim.x + threadIdx.x;
    if (k >= NG * NK) return;
    const float* c = cb + (size_t)k * DDIM;
    float blk[4];
#pragma unroll
    for (int b = 0; b < 4; ++b) {
        const float* p = c + b * 128;
        float s[16];
#pragma unroll
        for (int l = 0; l < 16; ++l) {
            float x0 = p[l],      x1 = p[l + 16], x2 = p[l + 32], x3 = p[l + 48];
            float x4 = p[l + 64], x5 = p[l + 80], x6 = p[l + 96], x7 = p[l + 112];
            float pa = x0 * x0 + x4 * x4;
            float pb = x1 * x1 + x5 * x5;
            float pc = x2 * x2 + x6 * x6;
            float pd = x3 * x3 + x7 * x7;
            s[l] = (pa + pb) + (pc + pd);
        }
        float h[8];
#pragma unroll
        for (int l = 0; l < 8; ++l) h[l] = s[l] + s[l + 8];
        float q[4];
#pragma unroll
        for (int l = 0; l < 4; ++l) q[l] = h[l] + h[l + 4];
        float r0 = q[0] + q[2];
        float r1 = q[1] + q[3];
        blk[b] = r0 + r1;
    }
    float total = (blk[0] + blk[1]) + (blk[2] + blk[3]);
    halfnorm[k] = 0.5f * total;
}

// ---------------------------------------------------------------------------
// Codebook transpose: cbT[g][d][cw] = cb[g][cw][d]. Coalesced both sides via
// a padded 32x32 LDS tile. Bit-exact copy.
// ---------------------------------------------------------------------------
__global__ void rvq_transpose(const float* __restrict__ cb,
                              float* __restrict__ cbT) {
    __shared__ float tile[32][33];
    const int g   = blockIdx.z;
    const int cw0 = blockIdx.x * 32;
    const int d0  = blockIdx.y * 32;
    const int tx  = threadIdx.x, ty = threadIdx.y;   // 32 x 8
    const float* src = cb + ((size_t)g * NK + cw0) * DDIM + d0;
#pragma unroll
    for (int ph = 0; ph < 4; ++ph)
        tile[ty + ph * 8][tx] = src[(size_t)(ty + ph * 8) * DDIM + tx];
    __syncthreads();
    float* dst = cbT + ((size_t)g * DDIM + d0) * NK + cw0;
#pragma unroll
    for (int ph = 0; ph < 4; ++ph)
        dst[(size_t)(ty + ph * 8) * NK + tx] = tile[tx][ty + ph * 8];
}

// 4-k step, full TC=8 (K-block 1). A: TR wave-uniform LDS b128 broadcasts.
// BV: [0..3] = cw0+{0..3}, [4..7] = cw0+256+{0..3}. dd asc within step,
// steps asc -> strictly ascending k per accumulator chain.
#define STEP8(ACC, BV, KB)                                                   \
    _Pragma("unroll")                                                        \
    for (int r = 0; r < TR; ++r) {                                           \
        float4 av = *(const float4*)&resid[(r0 + r) * DDIM + (KB)];          \
        const float* avf = (const float*)&av;                                \
        _Pragma("unroll")                                                    \
        for (int dd = 0; dd < 4; ++dd) {                                     \
            const float a = avf[dd];                                         \
            const float* g1 = (const float*)&BV[dd];                         \
            const float* g2 = (const float*)&BV[4 + dd];                     \
            ACC[r][0] = fmaf(a, g1[0], ACC[r][0]);                           \
            ACC[r][1] = fmaf(a, g1[1], ACC[r][1]);                           \
            ACC[r][2] = fmaf(a, g1[2], ACC[r][2]);                           \
            ACC[r][3] = fmaf(a, g1[3], ACC[r][3]);                           \
            ACC[r][4] = fmaf(a, g2[0], ACC[r][4]);                           \
            ACC[r][5] = fmaf(a, g2[1], ACC[r][5]);                           \
            ACC[r][6] = fmaf(a, g2[2], ACC[r][6]);                           \
            ACC[r][7] = fmaf(a, g2[3], ACC[r][7]);                           \
        }                                                                    \
    }

#define LOADB8(DST, ROW)                                                     \
    _Pragma("unroll")                                                        \
    for (int dd = 0; dd < 4; ++dd) {                                         \
        DST[dd]     = *(const float4*)(bp + (size_t)((ROW) + dd) * NK);      \
        DST[4 + dd] = *(const float4*)(bp + (size_t)((ROW) + dd) * NK + 256);\
    }

// 4-k step, one TC=4 half (K-block 2). BH[dd] = row (KB+dd), 4 consecutive
// cols at offset JOFF (0 or 256) from cw0.
#define STEP4(ACC, BH, KB)                                                   \
    _Pragma("unroll")                                                        \
    for (int r = 0; r < TR; ++r) {                                           \
        float4 av = *(const float4*)&resid[(r0 + r) * DDIM + (KB)];          \
        const float* avf = (const float*)&av;                                \
        _Pragma("unroll")                                                    \
        for (int dd = 0; dd < 4; ++dd) {                                     \
            const float a = avf[dd];                                         \
            const float* bf = (const float*)&BH[dd];                         \
            ACC[r][0] = fmaf(a, bf[0], ACC[r][0]);                           \
            ACC[r][1] = fmaf(a, bf[1], ACC[r][1]);                           \
            ACC[r][2] = fmaf(a, bf[2], ACC[r][2]);                           \
            ACC[r][3] = fmaf(a, bf[3], ACC[r][3]);                           \
        }                                                                    \
    }

#define LOADB4(DST, ROW, JOFF)                                               \
    _Pragma("unroll")                                                        \
    for (int dd = 0; dd < 4; ++dd)                                           \
        DST[dd] = *(const float4*)(bp + (size_t)((ROW) + dd) * NK + (JOFF));

// ---------------------------------------------------------------------------
// Fused: residual VQ (4 stages, np-fp32-emulated scoring; B from transposed
// codebook in global/L2, A from LDS, barrier-free k-loop) + reference-order
// quantized sum + straight-through + MLP (512->128->128->7).
// ---------------------------------------------------------------------------
__global__ __launch_bounds__(NTHREADS, 2) void rvq_mlp_fused(
    const float* __restrict__ z, const float* __restrict__ cb,
    const float* __restrict__ cbT, const float* __restrict__ halfnorm,
    const float* __restrict__ w1, const float* __restrict__ b1,
    const float* __restrict__ w2, const float* __restrict__ b2,
    const float* __restrict__ w3, const float* __restrict__ b3,
    float* __restrict__ out) {
    extern __shared__ char smem[];
    float* resid = (float*)smem;                       // [BM][DDIM]; later h1/h2
    float* redS  = (float*)(smem + OFF_AUX);           // [2][BM]
    int*   redI  = (int*)(smem + OFF_AUX + 256);       // [2][BM]
    int*   idx_s = (int*)(smem + OFF_AUX + 512);       // [NG][BM]

    const int tid = threadIdx.x;
    const size_t row0 = (size_t)blockIdx.x * BM;

    // ---- 1) load z tile into LDS ----
    {
        const float4* src = (const float4*)(z + row0 * DDIM);
        float4* dst = (float4*)resid;
#pragma unroll
        for (int i = 0; i < (BM * DDIM / 4) / NTHREADS; ++i)
            dst[tid + i * NTHREADS] = src[tid + i * NTHREADS];
    }
    __syncthreads();

    const int cg    = tid & 63;       // lane
    const int wv    = tid >> 6;       // wave 0..7
    const int rgrp  = wv & 3;         // row-group (8 rows each)
    const int cwgrp = wv >> 2;        // cw-group (512 cw each)
    const int r0    = rgrp * TR;
    const int cw0   = cwgrp * 512 + cg * 4;   // lane cols: cw0+{0..3}, +256+{0..3}

    // ---- 2) residual VQ stages ----
    for (int g = 0; g < NG; ++g) {
        const float* Cg = cb + (size_t)g * NK * DDIM;      // row-major (updates)
        const float* Tg = cbT + (size_t)g * DDIM * NK;     // transposed (scores)
        const float* hn = halfnorm + g * NK;
        const float* bp = Tg + cw0;

        // ---- K-block 1: k = 0..383, all 8 codewords (accA = 64 regs) ----
        float accA[TR][TC];
#pragma unroll
        for (int r = 0; r < TR; ++r)
#pragma unroll
            for (int j = 0; j < TC; ++j) accA[r][j] = 0.f;
        {
            float4 bv[8];
#pragma unroll 1
            for (int d4 = 0; d4 < KSPLIT; d4 += 4) {
                LOADB8(bv, d4)
                STEP8(accA, bv, d4)
            }
        }

        float sb[TR]; int ib[TR];
#pragma unroll
        for (int r = 0; r < TR; ++r) { sb[r] = -3.4e38f; ib[r] = 0; }

        // ---- K-block 2, half 1: j=0..3 (cols cw0+{0..3}); fold right away
        //      (frees accB; candidates ascending) ----
        {
            float accB[TR][4];
#pragma unroll
            for (int r = 0; r < TR; ++r)
#pragma unroll
                for (int j = 0; j < 4; ++j) accB[r][j] = 0.f;
            float4 bh[4];
#pragma unroll 1
            for (int d4 = KSPLIT; d4 < DDIM; d4 += 4) {
                LOADB4(bh, d4, 0)
                STEP4(accB, bh, d4)
            }
#pragma unroll
            for (int j = 0; j < 4; ++j) {
                const int cod = cw0 + j;
                const float hnv = hn[cod];
#pragma unroll
                for (int r = 0; r < TR; ++r) {
                    float s = (accA[r][j] + accB[r][j]) - hnv;
                    if (s > sb[r]) { sb[r] = s; ib[r] = cod; }
                }
            }
        }

        // ---- K-block 2, half 2: j=4..7 (cols cw0+256+{0..3}) ----
        {
            float accB[TR][4];
#pragma unroll
            for (int r = 0; r < TR; ++r)
#pragma unroll
                for (int j = 0; j < 4; ++j) accB[r][j] = 0.f;
            float4 bh[4];
#pragma unroll 1
            for (int d4 = KSPLIT; d4 < DDIM; d4 += 4) {
                LOADB4(bh, d4, 256)
                STEP4(accB, bh, d4)
            }
#pragma unroll
            for (int j = 0; j < 4; ++j) {
                const int cod = cw0 + 256 + j;
                const float hnv = hn[cod];
#pragma unroll
                for (int r = 0; r < TR; ++r) {
                    float s = (accA[r][4 + j] + accB[r][j]) - hnv;
                    if (s > sb[r]) { sb[r] = s; ib[r] = cod; }
                }
            }
        }

        // ---- butterfly argmax within wave (ties -> lower index) ----
#pragma unroll
        for (int m = 32; m >= 1; m >>= 1) {
#pragma unroll
            for (int r = 0; r < TR; ++r) {
                float os = __shfl_xor(sb[r], m, 64);
                int   oi = __shfl_xor(ib[r], m, 64);
                if (os > sb[r] || (os == sb[r] && oi < ib[r])) {
                    sb[r] = os; ib[r] = oi;
                }
            }
        }
        if (cg == 0) {
#pragma unroll
            for (int r = 0; r < TR; ++r) {
                redS[cwgrp * BM + r0 + r] = sb[r];
                redI[cwgrp * BM + r0 + r] = ib[r];
            }
        }
        __syncthreads();
        // combine the two cw-groups per row (global first-occurrence ties)
        if (tid < BM) {
            float sA = redS[tid], sB = redS[BM + tid];
            int   iA = redI[tid], iB = redI[BM + tid];
            idx_s[g * BM + tid] =
                (sB > sA || (sB == sA && iB < iA)) ? iB : iA;
        }
        __syncthreads();

        // ---- residual -= chosen codeword (exact fp32); skip after last ----
        if (g < NG - 1) {
            const int row = tid >> 4;
            const int sub = tid & 15;
            const float4* crow =
                (const float4*)(Cg + (size_t)idx_s[g * BM + row] * DDIM);
            float4* rrow = (float4*)&resid[row * DDIM];
#pragma unroll
            for (int k = 0; k < 8; ++k) {
                int p = sub + k * 16;
                float4 rv = rrow[p], cv = crow[p];
                rv.x -= cv.x; rv.y -= cv.y; rv.z -= cv.z; rv.w -= cv.w;
                rrow[p] = rv;
            }
            __syncthreads();
        }
    }

    // ---- 3) st = z + (zq - z), zq in reference order (((0+q0)+q1)+q2)+q3 ----
    {
        const int row = tid >> 4;
        const int sub = tid & 15;
        const float4* zrow = (const float4*)(z + (row0 + row) * DDIM);
        float4* rrow = (float4*)&resid[row * DDIM];
        const float4* c0 = (const float4*)(cb + ((size_t)0 * NK + idx_s[0 * BM + row]) * DDIM);
        const float4* c1 = (const float4*)(cb + ((size_t)1 * NK + idx_s[1 * BM + row]) * DDIM);
        const float4* c2 = (const float4*)(cb + ((size_t)2 * NK + idx_s[2 * BM + row]) * DDIM);
        const float4* c3 = (const float4*)(cb + ((size_t)3 * NK + idx_s[3 * BM + row]) * DDIM);
#pragma unroll
        for (int k = 0; k < 8; ++k) {
            int p = sub + k * 16;
            float4 q0 = c0[p], q1 = c1[p], q2 = c2[p], q3 = c3[p];
            float4 q;
            q.x = ((q0.x + q1.x) + q2.x) + q3.x;
            q.y = ((q0.y + q1.y) + q2.y) + q3.y;
            q.z = ((q0.z + q1.z) + q2.z) + q3.z;
            q.w = ((q0.w + q1.w) + q2.w) + q3.w;
            float4 zv = zrow[p];
            float4 st;
            st.x = zv.x + (q.x - zv.x);
            st.y = zv.y + (q.y - zv.y);
            st.z = zv.z + (q.z - zv.z);
            st.w = zv.w + (q.w - zv.w);
            rrow[p] = st;
        }
    }
    __syncthreads();

    const int colg = tid & 31;
    const int rowg = tid >> 5;
    const int c0_  = colg * 4;
    const int hr0  = rowg * 2;

    float* h1buf = resid;              // [BM][NH], overwrites st rows 0..7
    float* h2buf = resid + BM * NH;    // [BM][NH], overwrites st rows 8..15

    // ---- 4) h1 = relu(st @ w1 + b1) -> regs -> barrier -> h1buf ----
    {
        float acc[2][4] = {{0.f, 0.f, 0.f, 0.f}, {0.f, 0.f, 0.f, 0.f}};
        for (int d = 0; d < DDIM; d += 4) {
            float4 a0 = *(const float4*)&resid[hr0 * DDIM + d];
            float4 a1 = *(const float4*)&resid[(hr0 + 1) * DDIM + d];
            float a0f[4] = {a0.x, a0.y, a0.z, a0.w};
            float a1f[4] = {a1.x, a1.y, a1.z, a1.w};
#pragma unroll
            for (int dd = 0; dd < 4; ++dd) {
                float4 wv2 = *(const float4*)&w1[(size_t)(d + dd) * NH + c0_];
                acc[0][0] = fmaf(a0f[dd], wv2.x, acc[0][0]);
                acc[0][1] = fmaf(a0f[dd], wv2.y, acc[0][1]);
                acc[0][2] = fmaf(a0f[dd], wv2.z, acc[0][2]);
                acc[0][3] = fmaf(a0f[dd], wv2.w, acc[0][3]);
                acc[1][0] = fmaf(a1f[dd], wv2.x, acc[1][0]);
                acc[1][1] = fmaf(a1f[dd], wv2.y, acc[1][1]);
                acc[1][2] = fmaf(a1f[dd], wv2.z, acc[1][2]);
                acc[1][3] = fmaf(a1f[dd], wv2.w, acc[1][3]);
            }
        }
        float4 bv = *(const float4*)&b1[c0_];
        float bf[4] = {bv.x, bv.y, bv.z, bv.w};
        __syncthreads();   // all st reads complete before overwriting resid
#pragma unroll
        for (int r = 0; r < 2; ++r) {
            float4 o;
            o.x = fmaxf(acc[r][0] + bf[0], 0.f);
            o.y = fmaxf(acc[r][1] + bf[1], 0.f);
            o.z = fmaxf(acc[r][2] + bf[2], 0.f);
            o.w = fmaxf(acc[r][3] + bf[3], 0.f);
            *(float4*)&h1buf[(hr0 + r) * NH + c0_] = o;
        }
    }
    __syncthreads();

    // ---- 5) h2 = relu(h1 @ w2 + b2) -> regs -> barrier -> h2buf ----
    {
        float acc[2][4] = {{0.f, 0.f, 0.f, 0.f}, {0.f, 0.f, 0.f, 0.f}};
        for (int d = 0; d < NH; d += 4) {
            float4 a0 = *(const float4*)&h1buf[hr0 * NH + d];
            float4 a1 = *(const float4*)&h1buf[(hr0 + 1) * NH + d];
            float a0f[4] = {a0.x, a0.y, a0.z, a0.w};
            float a1f[4] = {a1.x, a1.y, a1.z, a1.w};
#pragma unroll
            for (int dd = 0; dd < 4; ++dd) {
                float4 wv2 = *(const float4*)&w2[(size_t)(d + dd) * NH + c0_];
                acc[0][0] = fmaf(a0f[dd], wv2.x, acc[0][0]);
                acc[0][1] = fmaf(a0f[dd], wv2.y, acc[0][1]);
                acc[0][2] = fmaf(a0f[dd], wv2.z, acc[0][2]);
                acc[0][3] = fmaf(a0f[dd], wv2.w, acc[0][3]);
                acc[1][0] = fmaf(a1f[dd], wv2.x, acc[1][0]);
                acc[1][1] = fmaf(a1f[dd], wv2.y, acc[1][1]);
                acc[1][2] = fmaf(a1f[dd], wv2.z, acc[1][2]);
                acc[1][3] = fmaf(a1f[dd], wv2.w, acc[1][3]);
            }
        }
        float4 bv = *(const float4*)&b2[c0_];
        float bf[4] = {bv.x, bv.y, bv.z, bv.w};
        __syncthreads();   // all h1 reads complete (h2buf overlaps nothing of h1)
#pragma unroll
        for (int r = 0; r < 2; ++r) {
            float4 o;
            o.x = fmaxf(acc[r][0] + bf[0], 0.f);
            o.y = fmaxf(acc[r][1] + bf[1], 0.f);
            o.z = fmaxf(acc[r][2] + bf[2], 0.f);
            o.w = fmaxf(acc[r][3] + bf[3], 0.f);
            *(float4*)&h2buf[(hr0 + r) * NH + c0_] = o;
        }
    }
    __syncthreads();

    // ---- 6) out = h2 @ w3 + b3 ----
    if (tid < BM * NA) {
        const int r = tid / NA;
        const int a = tid - r * NA;
        const float* h2r = &h2buf[r * NH];
        float s = b3[a];
        for (int h = 0; h < NH; ++h)
            s = fmaf(h2r[h], w3[(size_t)h * NA + a], s);
        out[(row0 + r) * NA + a] = s;
    }
}

extern "C" void kernel_launch(void* const* d_in, const int* in_sizes, int n_in,
                              void* d_out, int out_size, void* d_ws, size_t ws_size,
                              hipStream_t stream) {
    const float* z  = (const float*)d_in[0];
    const float* cb = (const float*)d_in[1];
    const float* w1 = (const float*)d_in[2];
    const float* b1 = (const float*)d_in[3];
    const float* w2 = (const float*)d_in[4];
    const float* b2 = (const float*)d_in[5];
    const float* w3 = (const float*)d_in[6];
    const float* b3 = (const float*)d_in[7];
    float* out = (float*)d_out;

    float* halfnorm = (float*)d_ws;             // NG*NK floats = 16 KB
    float* cbT      = (float*)d_ws + NG * NK;   // NG*DDIM*NK floats = 8 MB

    (void)hipFuncSetAttribute((const void*)rvq_mlp_fused,
                              hipFuncAttributeMaxDynamicSharedMemorySize,
                              LDS_BYTES);

    rvq_norms_np<<<dim3((NG * NK + 255) / 256), dim3(256), 0, stream>>>(cb, halfnorm);
    rvq_transpose<<<dim3(NK / 32, DDIM / 32, NG), dim3(32, 8), 0, stream>>>(cb, cbT);
    rvq_mlp_fused<<<dim3(B_ROWS / BM), dim3(NTHREADS), LDS_BYTES, stream>>>(
        z, cb, cbT, halfnorm, w1, b1, w2, b2, w3, b3, out);
}